// Round 3
// baseline (746.277 us; speedup 1.0000x reference)
//
#include <hip/hip_runtime.h>
#include <stdint.h>

#define BATCH 8
#define NPTS 8192
#define NGRP 512
#define KNN 32
#define NCH 6

#define FPS_T 1024
#define FPS_PPT (NPTS / FPS_T)   // 8 points per thread
#define FPS_NW (FPS_T / 64)      // 16 waves

// --------- FPS kernel: one block per batch, 16 waves/CU for latency hiding ---------
__global__ __launch_bounds__(FPS_T) void fps_kernel(const float* __restrict__ pts,
                                                    float* __restrict__ out_ctr) {
    __shared__ float xs[NPTS], ys[NPTS], zs[NPTS];
    __shared__ unsigned long long slots[2][FPS_NW];

    const int b   = blockIdx.x;
    const int tid = threadIdx.x;
    const float* base = pts + (size_t)b * NPTS * NCH;

    float x[FPS_PPT], y[FPS_PPT], z[FPS_PPT], dist[FPS_PPT];
#pragma unroll
    for (int j = 0; j < FPS_PPT; ++j) {
        int p = tid + j * FPS_T;
        x[j] = base[p * NCH + 0];
        y[j] = base[p * NCH + 1];
        z[j] = base[p * NCH + 2];
        xs[p] = x[j]; ys[p] = y[j]; zs[p] = z[j];
        dist[j] = 1e10f;
    }
    __syncthreads();

    int far = 0;
    float* ctr = out_ctr + (size_t)b * NGRP * 3;

    for (int g = 0; g < NGRP; ++g) {
        // centroid broadcast from LDS (all lanes same address -> broadcast)
        float cx = xs[far], cy = ys[far], cz = zs[far];
        if (tid == 0) {
            ctr[g * 3 + 0] = cx;
            ctr[g * 3 + 1] = cy;
            ctr[g * 3 + 2] = cz;
        }

        // min-dist update + local argmax (first-index tie-break: ascending j,
        // strict >). numpy semantics: (dx^2 + dy^2) + dz^2, no FMA.
        float bestv = -1.0f;
        int bestj = 0;
#pragma unroll
        for (int j = 0; j < FPS_PPT; ++j) {
            float dx = __fsub_rn(x[j], cx);
            float dy = __fsub_rn(y[j], cy);
            float dz = __fsub_rn(z[j], cz);
            float d = __fadd_rn(__fadd_rn(__fmul_rn(dx, dx), __fmul_rn(dy, dy)),
                                __fmul_rn(dz, dz));
            float nd = fminf(dist[j], d);
            dist[j] = nd;
            if (nd > bestv) { bestv = nd; bestj = j; }
        }
        int bestp = tid + bestj * FPS_T;
        // max-key with min-index tie-break (dist >= 0 so raw bits monotone)
        unsigned long long key =
            ((unsigned long long)__float_as_uint(bestv) << 13) |
            (unsigned)(8191 - bestp);

        // wave-level max reduce
#pragma unroll
        for (int s = 32; s > 0; s >>= 1) {
            unsigned long long o = __shfl_xor(key, s, 64);
            key = (o > key) ? o : key;
        }
        int wid = tid >> 6;
        if ((tid & 63) == 0) slots[g & 1][wid] = key;
        __syncthreads();

        unsigned long long best = slots[g & 1][0];
#pragma unroll
        for (int w = 1; w < FPS_NW; ++w) {
            unsigned long long o = slots[g & 1][w];
            best = (o > best) ? o : best;
        }
        far = 8191 - (int)(best & 8191ULL);
    }
}

// --------- SoA transpose + per-point |x|^2 (matches jnp.sum(xyz**2,-1)) ---------
__global__ __launch_bounds__(256) void soa_kernel(const float* __restrict__ pts,
                                                  float* __restrict__ xs,
                                                  float* __restrict__ ys,
                                                  float* __restrict__ zs,
                                                  float* __restrict__ xx) {
    int i = blockIdx.x * blockDim.x + threadIdx.x;  // b*NPTS + p
    const float* s = pts + (size_t)i * NCH;
    float x = s[0], y = s[1], z = s[2];
    xs[i] = x; ys[i] = y; zs[i] = z;
    xx[i] = __fadd_rn(__fadd_rn(__fmul_rn(x, x), __fmul_rn(y, y)), __fmul_rn(z, z));
}

// --------- kNN keys ---------
// dot: einsum inner loop FMA-contracted ascending: fma(cz,z, fma(cy,y, rn(cx*x)))
// d2 = (cc + xx) - 2*dot, each op rounded.
__device__ __forceinline__ unsigned long long pack_key(float d2, int p) {
    unsigned int bits = __float_as_uint(d2);
    unsigned int ord = bits ^ ((unsigned)((int)bits >> 31) | 0x80000000u);
    return ((unsigned long long)ord << 13) | (unsigned)p;
}

__device__ __forceinline__ unsigned long long knn_key_aos(const float* __restrict__ base,
                                                          int p, float cx, float cy,
                                                          float cz, float cc) {
    float x = base[p * NCH + 0];
    float y = base[p * NCH + 1];
    float z = base[p * NCH + 2];
    float xx = __fadd_rn(__fadd_rn(__fmul_rn(x, x), __fmul_rn(y, y)), __fmul_rn(z, z));
    float dt = fmaf(cz, z, fmaf(cy, y, __fmul_rn(cx, x)));
    float d2 = __fsub_rn(__fadd_rn(cc, xx), __fmul_rn(2.0f, dt));
    return pack_key(d2, p);
}

__device__ __forceinline__ unsigned long long knn_key_soa(const float* __restrict__ xs,
                                                          const float* __restrict__ ys,
                                                          const float* __restrict__ zs,
                                                          const float* __restrict__ xx,
                                                          int i, int p, float cx,
                                                          float cy, float cz, float cc) {
    float x = xs[i], y = ys[i], z = zs[i], q = xx[i];
    float dt = fmaf(cz, z, fmaf(cy, y, __fmul_rn(cx, x)));
    float d2 = __fsub_rn(__fadd_rn(cc, q), __fmul_rn(2.0f, dt));
    return pack_key(d2, p);
}

// --------- kNN + gather: one wave per (b,g) center ---------
template <int SOA>
__global__ __launch_bounds__(64) void knn_kernel(const float* __restrict__ pts,
                                                 const float* __restrict__ ctr,
                                                 float* __restrict__ out_nb,
                                                 const float* __restrict__ xs,
                                                 const float* __restrict__ ys,
                                                 const float* __restrict__ zs,
                                                 const float* __restrict__ xx) {
    const int bg   = blockIdx.x;       // b*NGRP + g
    const int b    = bg >> 9;
    const int lane = threadIdx.x & 63;
    const float* base = pts + (size_t)b * NPTS * NCH;
    const int ibase = b * NPTS;

    const float cx = ctr[bg * 3 + 0];
    const float cy = ctr[bg * 3 + 1];
    const float cz = ctr[bg * 3 + 2];
    const float cc = __fadd_rn(__fadd_rn(__fmul_rn(cx, cx), __fmul_rn(cy, cy)),
                               __fmul_rn(cz, cz));

    // chunk 0 -> bitonic sort 64 keys across the wave (ascending by lane)
    unsigned long long R = SOA
        ? knn_key_soa(xs, ys, zs, xx, ibase + lane, lane, cx, cy, cz, cc)
        : knn_key_aos(base, lane, cx, cy, cz, cc);
#pragma unroll
    for (int k = 2; k <= 64; k <<= 1) {
#pragma unroll
        for (int j = k >> 1; j > 0; j >>= 1) {
            unsigned long long o = __shfl_xor(R, j, 64);
            bool takeMin = (((lane & k) == 0) == ((lane & j) == 0));
            unsigned long long mn = (o < R) ? o : R;
            unsigned long long mx = (o < R) ? R : o;
            R = takeMin ? mn : mx;
        }
    }
    unsigned long long R31 = __shfl(R, 31, 64);

    // stream remaining chunks; insert only candidates beating current 32nd
    for (int c = 1; c < NPTS / 64; ++c) {
        int p = c * 64 + lane;
        unsigned long long key = SOA
            ? knn_key_soa(xs, ys, zs, xx, ibase + p, p, cx, cy, cz, cc)
            : knn_key_aos(base, p, cx, cy, cz, cc);
        unsigned long long qual = __ballot(key < R31);
        while (qual) {
            int src = __ffsll(qual) - 1;
            qual &= qual - 1;
            unsigned long long bk = __shfl(key, src, 64);
            int rank = __popcll(__ballot(R < bk));
            unsigned long long Rp = __shfl_up(R, 1, 64);
            R = (lane == rank) ? bk : ((lane > rank) ? Rp : R);
            R31 = __shfl(R, 31, 64);
        }
    }

    // gather: lanes 0..31 hold the sorted top-32 (ascending d2, index tie-break)
    if (lane < KNN) {
        int idx = (int)(R & 8191ULL);
        const float* s = base + (size_t)idx * NCH;
        float* d = out_nb + ((size_t)bg * KNN + lane) * NCH;
        d[0] = s[0] - cx;
        d[1] = s[1] - cy;
        d[2] = s[2] - cz;
        d[3] = s[3];
        d[4] = s[4];
        d[5] = s[5];
    }
}

extern "C" void kernel_launch(void* const* d_in, const int* in_sizes, int n_in,
                              void* d_out, int out_size, void* d_ws, size_t ws_size,
                              hipStream_t stream) {
    const float* pts = (const float*)d_in[0];
    float* out = (float*)d_out;
    float* out_nb  = out;                                    // (8,512,32,6)
    float* out_ctr = out + (size_t)BATCH * NGRP * KNN * NCH; // (8,512,3)

    const size_t npts_tot = (size_t)BATCH * NPTS;
    float* xs = (float*)d_ws;
    float* ys = xs + npts_tot;
    float* zs = ys + npts_tot;
    float* xx = zs + npts_tot;
    bool use_soa = ws_size >= 4 * npts_tot * sizeof(float);

    if (use_soa) {
        hipLaunchKernelGGL(soa_kernel, dim3(npts_tot / 256), dim3(256), 0, stream,
                           pts, xs, ys, zs, xx);
    }
    hipLaunchKernelGGL(fps_kernel, dim3(BATCH), dim3(FPS_T), 0, stream, pts, out_ctr);
    if (use_soa) {
        hipLaunchKernelGGL((knn_kernel<1>), dim3(BATCH * NGRP), dim3(64), 0, stream,
                           pts, out_ctr, out_nb, xs, ys, zs, xx);
    } else {
        hipLaunchKernelGGL((knn_kernel<0>), dim3(BATCH * NGRP), dim3(64), 0, stream,
                           pts, out_ctr, out_nb, xs, ys, zs, xx);
    }
}

// Round 4
// 598.750 us; speedup vs baseline: 1.2464x; 1.2464x over previous
//
#include <hip/hip_runtime.h>
#include <stdint.h>

#define BATCH 8
#define NPTS 8192
#define NGRP 512
#define KNN 32
#define NCH 6

#define FPS_T 256
#define FPS_PPT (NPTS / FPS_T)   // 32 points per thread
#define FPS_NW (FPS_T / 64)      // 4 waves

typedef float f2 __attribute__((ext_vector_type(2)));

// packed f32 ops (VOP3P): 2 points per instruction, IEEE rn per lane —
// bit-identical to scalar __fadd_rn/__fmul_rn.
__device__ __forceinline__ f2 pk_add(f2 a, f2 b) {
    f2 d;
    asm("v_pk_add_f32 %0, %1, %2" : "=v"(d) : "v"(a), "v"(b));
    return d;
}
__device__ __forceinline__ f2 pk_mul(f2 a, f2 b) {
    f2 d;
    asm("v_pk_mul_f32 %0, %1, %2" : "=v"(d) : "v"(a), "v"(b));
    return d;
}

// one butterfly stage of 64-bit max via DPP (VALU latency, no LDS pipe).
// CTRL: 0xB1=quad_perm[1,0,3,2](xor1) 0x4E=[2,3,0,1](xor2)
//       0x141=row_half_mirror(xor7)   0x140=row_mirror(xor15)
// masks {1,2,7,15} generate the full 16-lane row; then shfl_xor 16/32.
template <int CTRL>
__device__ __forceinline__ unsigned long long dpp_max(unsigned long long k) {
    int lo = (int)(unsigned)k;
    int hi = (int)(unsigned)(k >> 32);
    int plo = __builtin_amdgcn_update_dpp(0, lo, CTRL, 0xF, 0xF, false);
    int phi = __builtin_amdgcn_update_dpp(0, hi, CTRL, 0xF, 0xF, false);
    unsigned long long o =
        ((unsigned long long)(unsigned)phi << 32) | (unsigned)(unsigned)plo;
    return (o > k) ? o : k;
}

// --------- FPS kernel: one block per batch, 256 threads ---------
__global__ __launch_bounds__(FPS_T) void fps_kernel(const float* __restrict__ pts,
                                                    float* __restrict__ out_ctr) {
    __shared__ float xs[NPTS], ys[NPTS], zs[NPTS];
    __shared__ unsigned long long slots[2][FPS_NW];

    const int b   = blockIdx.x;
    const int tid = threadIdx.x;
    const float* base = pts + (size_t)b * NPTS * NCH;

    f2 x2[FPS_PPT / 2], y2[FPS_PPT / 2], z2[FPS_PPT / 2], dist2[FPS_PPT / 2];
#pragma unroll
    for (int i = 0; i < FPS_PPT / 2; ++i) {
        int p0 = tid + (2 * i) * FPS_T;
        int p1 = tid + (2 * i + 1) * FPS_T;
        float xa = base[p0 * NCH + 0], ya = base[p0 * NCH + 1], za = base[p0 * NCH + 2];
        float xb = base[p1 * NCH + 0], yb = base[p1 * NCH + 1], zb = base[p1 * NCH + 2];
        x2[i] = (f2){xa, xb};
        y2[i] = (f2){ya, yb};
        z2[i] = (f2){za, zb};
        dist2[i] = (f2){1e10f, 1e10f};
        xs[p0] = xa; ys[p0] = ya; zs[p0] = za;
        xs[p1] = xb; ys[p1] = yb; zs[p1] = zb;
    }
    __syncthreads();

    int far = 0;
    float* ctr = out_ctr + (size_t)b * NGRP * 3;

    for (int g = 0; g < NGRP; ++g) {
        // centroid broadcast from LDS
        float cx = xs[far], cy = ys[far], cz = zs[far];
        if (tid == 0) {
            ctr[g * 3 + 0] = cx;
            ctr[g * 3 + 1] = cy;
            ctr[g * 3 + 2] = cz;
        }
        f2 ncx = (f2){-cx, -cx};
        f2 ncy = (f2){-cy, -cy};
        f2 ncz = (f2){-cz, -cz};

        // min-dist update + argmax (first-index tie-break: ascending j,
        // strict >). numpy semantics: (dx^2 + dy^2) + dz^2, each op rn,
        // no FMA. sub(x,c) == add(x,-c) exactly.
        float bestv = -1.0f;
        int bestj = 0;
#pragma unroll
        for (int i = 0; i < FPS_PPT / 2; ++i) {
            f2 dx = pk_add(x2[i], ncx);
            f2 dy = pk_add(y2[i], ncy);
            f2 dz = pk_add(z2[i], ncz);
            f2 sx = pk_mul(dx, dx);
            f2 sy = pk_mul(dy, dy);
            f2 t  = pk_add(sx, sy);
            f2 sz = pk_mul(dz, dz);
            f2 d  = pk_add(t, sz);
            float nd0 = fminf(dist2[i].x, d.x);
            float nd1 = fminf(dist2[i].y, d.y);
            dist2[i].x = nd0;
            dist2[i].y = nd1;
            if (nd0 > bestv) { bestv = nd0; bestj = 2 * i; }
            if (nd1 > bestv) { bestv = nd1; bestj = 2 * i + 1; }
        }
        int bestp = tid + bestj * FPS_T;
        // max-key, min-index tie-break (dist >= 0 -> raw float bits monotone)
        unsigned long long key =
            ((unsigned long long)__float_as_uint(bestv) << 13) |
            (unsigned)(8191 - bestp);

        // wave-level max reduce: DPP for xor{1,2,7,15}, shfl for 16/32
        key = dpp_max<0xB1>(key);
        key = dpp_max<0x4E>(key);
        key = dpp_max<0x141>(key);
        key = dpp_max<0x140>(key);
        {
            unsigned long long o = __shfl_xor(key, 16, 64);
            key = (o > key) ? o : key;
            o = __shfl_xor(key, 32, 64);
            key = (o > key) ? o : key;
        }

        int wid = tid >> 6;
        if ((tid & 63) == 0) slots[g & 1][wid] = key;
        __syncthreads();

        unsigned long long best = slots[g & 1][0];
#pragma unroll
        for (int w = 1; w < FPS_NW; ++w) {
            unsigned long long o = slots[g & 1][w];
            best = (o > best) ? o : best;
        }
        far = 8191 - (int)(best & 8191ULL);
    }
}

// --------- SoA transpose + per-point |x|^2 (matches jnp.sum(xyz**2,-1)) ---------
__global__ __launch_bounds__(256) void soa_kernel(const float* __restrict__ pts,
                                                  float* __restrict__ xs,
                                                  float* __restrict__ ys,
                                                  float* __restrict__ zs,
                                                  float* __restrict__ xx) {
    int i = blockIdx.x * blockDim.x + threadIdx.x;  // b*NPTS + p
    const float* s = pts + (size_t)i * NCH;
    float x = s[0], y = s[1], z = s[2];
    xs[i] = x; ys[i] = y; zs[i] = z;
    xx[i] = __fadd_rn(__fadd_rn(__fmul_rn(x, x), __fmul_rn(y, y)), __fmul_rn(z, z));
}

// --------- kNN keys ---------
// dot: einsum inner loop FMA-contracted ascending: fma(cz,z, fma(cy,y, rn(cx*x)))
// d2 = (cc + xx) - 2*dot, each op rounded.
__device__ __forceinline__ unsigned long long pack_key(float d2, int p) {
    unsigned int bits = __float_as_uint(d2);
    unsigned int ord = bits ^ ((unsigned)((int)bits >> 31) | 0x80000000u);
    return ((unsigned long long)ord << 13) | (unsigned)p;
}

__device__ __forceinline__ unsigned long long knn_key_soa(const float* __restrict__ xs,
                                                          const float* __restrict__ ys,
                                                          const float* __restrict__ zs,
                                                          const float* __restrict__ xx,
                                                          int i, int p, float cx,
                                                          float cy, float cz, float cc) {
    float x = xs[i], y = ys[i], z = zs[i], q = xx[i];
    float dt = fmaf(cz, z, fmaf(cy, y, __fmul_rn(cx, x)));
    float d2 = __fsub_rn(__fadd_rn(cc, q), __fmul_rn(2.0f, dt));
    return pack_key(d2, p);
}

__device__ __forceinline__ unsigned long long knn_key_aos(const float* __restrict__ base,
                                                          int p, float cx, float cy,
                                                          float cz, float cc) {
    float x = base[p * NCH + 0];
    float y = base[p * NCH + 1];
    float z = base[p * NCH + 2];
    float xx = __fadd_rn(__fadd_rn(__fmul_rn(x, x), __fmul_rn(y, y)), __fmul_rn(z, z));
    float dt = fmaf(cz, z, fmaf(cy, y, __fmul_rn(cx, x)));
    float d2 = __fsub_rn(__fadd_rn(cc, xx), __fmul_rn(2.0f, dt));
    return pack_key(d2, p);
}

// --------- kNN + gather: one wave per (b,g) center ---------
template <int SOA>
__global__ __launch_bounds__(64) void knn_kernel(const float* __restrict__ pts,
                                                 const float* __restrict__ ctr,
                                                 float* __restrict__ out_nb,
                                                 const float* __restrict__ xs,
                                                 const float* __restrict__ ys,
                                                 const float* __restrict__ zs,
                                                 const float* __restrict__ xx) {
    const int bg   = blockIdx.x;       // b*NGRP + g
    const int b    = bg >> 9;
    const int lane = threadIdx.x & 63;
    const float* base = pts + (size_t)b * NPTS * NCH;
    const int ibase = b * NPTS;

    const float cx = ctr[bg * 3 + 0];
    const float cy = ctr[bg * 3 + 1];
    const float cz = ctr[bg * 3 + 2];
    const float cc = __fadd_rn(__fadd_rn(__fmul_rn(cx, cx), __fmul_rn(cy, cy)),
                               __fmul_rn(cz, cz));

    // chunk 0 -> bitonic sort 64 keys across the wave (ascending by lane)
    unsigned long long R = SOA
        ? knn_key_soa(xs, ys, zs, xx, ibase + lane, lane, cx, cy, cz, cc)
        : knn_key_aos(base, lane, cx, cy, cz, cc);
#pragma unroll
    for (int k = 2; k <= 64; k <<= 1) {
#pragma unroll
        for (int j = k >> 1; j > 0; j >>= 1) {
            unsigned long long o = __shfl_xor(R, j, 64);
            bool takeMin = (((lane & k) == 0) == ((lane & j) == 0));
            unsigned long long mn = (o < R) ? o : R;
            unsigned long long mx = (o < R) ? R : o;
            R = takeMin ? mn : mx;
        }
    }
    unsigned long long R31 = __shfl(R, 31, 64);

    // stream remaining chunks; insert only candidates beating current 32nd
    for (int c = 1; c < NPTS / 64; ++c) {
        int p = c * 64 + lane;
        unsigned long long key = SOA
            ? knn_key_soa(xs, ys, zs, xx, ibase + p, p, cx, cy, cz, cc)
            : knn_key_aos(base, p, cx, cy, cz, cc);
        unsigned long long qual = __ballot(key < R31);
        while (qual) {
            int src = __ffsll(qual) - 1;
            qual &= qual - 1;
            unsigned long long bk = __shfl(key, src, 64);
            int rank = __popcll(__ballot(R < bk));
            unsigned long long Rp = __shfl_up(R, 1, 64);
            R = (lane == rank) ? bk : ((lane > rank) ? Rp : R);
            R31 = __shfl(R, 31, 64);
        }
    }

    // gather: lanes 0..31 hold the sorted top-32 (ascending d2, index tie-break)
    if (lane < KNN) {
        int idx = (int)(R & 8191ULL);
        const float* s = base + (size_t)idx * NCH;
        float* d = out_nb + ((size_t)bg * KNN + lane) * NCH;
        d[0] = s[0] - cx;
        d[1] = s[1] - cy;
        d[2] = s[2] - cz;
        d[3] = s[3];
        d[4] = s[4];
        d[5] = s[5];
    }
}

extern "C" void kernel_launch(void* const* d_in, const int* in_sizes, int n_in,
                              void* d_out, int out_size, void* d_ws, size_t ws_size,
                              hipStream_t stream) {
    const float* pts = (const float*)d_in[0];
    float* out = (float*)d_out;
    float* out_nb  = out;                                    // (8,512,32,6)
    float* out_ctr = out + (size_t)BATCH * NGRP * KNN * NCH; // (8,512,3)

    const size_t npts_tot = (size_t)BATCH * NPTS;
    float* xs = (float*)d_ws;
    float* ys = xs + npts_tot;
    float* zs = ys + npts_tot;
    float* xx = zs + npts_tot;
    bool use_soa = ws_size >= 4 * npts_tot * sizeof(float);

    if (use_soa) {
        hipLaunchKernelGGL(soa_kernel, dim3(npts_tot / 256), dim3(256), 0, stream,
                           pts, xs, ys, zs, xx);
    }
    hipLaunchKernelGGL(fps_kernel, dim3(BATCH), dim3(FPS_T), 0, stream, pts, out_ctr);
    if (use_soa) {
        hipLaunchKernelGGL((knn_kernel<1>), dim3(BATCH * NGRP), dim3(64), 0, stream,
                           pts, out_ctr, out_nb, xs, ys, zs, xx);
    } else {
        hipLaunchKernelGGL((knn_kernel<0>), dim3(BATCH * NGRP), dim3(64), 0, stream,
                           pts, out_ctr, out_nb, xs, ys, zs, xx);
    }
}

// Round 5
// 572.741 us; speedup vs baseline: 1.3030x; 1.0454x over previous
//
#include <hip/hip_runtime.h>
#include <stdint.h>

#define BATCH 8
#define NPTS 8192
#define NGRP 512
#define KNN 32
#define NCH 6

#define FPS_T 512
#define FPS_PPT (NPTS / FPS_T)   // 16 points per thread
#define PAIRS (FPS_PPT / 2)      // 8 packed pairs
#define FPS_NW (FPS_T / 64)      // 8 waves

typedef float f2 __attribute__((ext_vector_type(2)));

// packed f32 ops (VOP3P): 2 points per instruction, IEEE rn per lane —
// bit-identical to scalar __fadd_rn/__fmul_rn. add(x,-c) == sub(x,c) exactly.
__device__ __forceinline__ f2 pk_add(f2 a, f2 b) {
    f2 d;
    asm("v_pk_add_f32 %0, %1, %2" : "=v"(d) : "v"(a), "v"(b));
    return d;
}
__device__ __forceinline__ f2 pk_mul(f2 a, f2 b) {
    f2 d;
    asm("v_pk_mul_f32 %0, %1, %2" : "=v"(d) : "v"(a), "v"(b));
    return d;
}

// f32 max with DPP-shifted source; lanes without a valid source keep v
// (old = v, so fmax(v,v) = v). Value-only reduce -> lane 63 holds wave max.
template <int CTRL>
__device__ __forceinline__ float dpp_fmax(float v) {
    int s = __builtin_amdgcn_update_dpp(__float_as_int(v), __float_as_int(v),
                                        CTRL, 0xF, 0xF, false);
    return fmaxf(v, __int_as_float(s));
}

// --------- FPS kernel: one block per batch, 512 threads ---------
__global__ __launch_bounds__(FPS_T) void fps_kernel(const float* __restrict__ pts,
                                                    float* __restrict__ out_ctr) {
    __shared__ float xs[NPTS], ys[NPTS], zs[NPTS];
    __shared__ float ctr_lds[NGRP * 3];
    __shared__ float wslot[FPS_NW];
    __shared__ unsigned int islot[2];

    const int b   = blockIdx.x;
    const int tid = threadIdx.x;
    const float* base = pts + (size_t)b * NPTS * NCH;

    f2 x2[PAIRS], y2[PAIRS], z2[PAIRS], dist2[PAIRS];
#pragma unroll
    for (int i = 0; i < PAIRS; ++i) {
        int p0 = tid + (2 * i) * FPS_T;
        int p1 = tid + (2 * i + 1) * FPS_T;
        float xa = base[p0 * NCH + 0], ya = base[p0 * NCH + 1], za = base[p0 * NCH + 2];
        float xb = base[p1 * NCH + 0], yb = base[p1 * NCH + 1], zb = base[p1 * NCH + 2];
        x2[i] = (f2){xa, xb};
        y2[i] = (f2){ya, yb};
        z2[i] = (f2){za, zb};
        dist2[i] = (f2){1e10f, 1e10f};
        xs[p0] = xa; ys[p0] = ya; zs[p0] = za;
        xs[p1] = xb; ys[p1] = yb; zs[p1] = zb;
    }
    __syncthreads();

    int far = 0;
    const int wid  = tid >> 6;
    const int lane = tid & 63;

    for (int g = 0; g < NGRP; ++g) {
        // centroid broadcast from LDS (same addr all lanes)
        float cx = xs[far], cy = ys[far], cz = zs[far];
        if (tid == 0) {
            // buffer centroid in LDS (global write deferred to kernel end:
            // keeps vmcnt==0 so __syncthreads never waits on HBM)
            ctr_lds[g * 3 + 0] = cx;
            ctr_lds[g * 3 + 1] = cy;
            ctr_lds[g * 3 + 2] = cz;
            islot[g & 1] = 0xFFFFFFFFu;   // reset this iter's index slot
        }
        f2 ncx = (f2){-cx, -cx};
        f2 ncy = (f2){-cy, -cy};
        f2 ncz = (f2){-cz, -cz};

        // min-dist update, value-only max tracking.
        // numpy semantics: (dx^2 + dy^2) + dz^2, each op rn, no FMA.
        float bestv = -1.0f;
#pragma unroll
        for (int i = 0; i < PAIRS; ++i) {
            f2 dx = pk_add(x2[i], ncx);
            f2 dy = pk_add(y2[i], ncy);
            f2 dz = pk_add(z2[i], ncz);
            f2 sx = pk_mul(dx, dx);
            f2 sy = pk_mul(dy, dy);
            f2 t  = pk_add(sx, sy);
            f2 sz = pk_mul(dz, dz);
            f2 d  = pk_add(t, sz);
            float nd0 = fminf(dist2[i].x, d.x);
            float nd1 = fminf(dist2[i].y, d.y);
            dist2[i].x = nd0;
            dist2[i].y = nd1;
            bestv = fmaxf(fmaxf(nd0, nd1), bestv);   // v_max3 candidate
        }

        // wave max (f32, DPP): row_shr 1/2/4/8 then row_bcast 15/31 -> lane63
        float m = bestv;
        m = dpp_fmax<0x111>(m);   // row_shr:1
        m = dpp_fmax<0x112>(m);   // row_shr:2
        m = dpp_fmax<0x114>(m);   // row_shr:4
        m = dpp_fmax<0x118>(m);   // row_shr:8
        m = dpp_fmax<0x142>(m);   // row_bcast:15
        m = dpp_fmax<0x143>(m);   // row_bcast:31
        if (lane == 63) wslot[wid] = m;
        __syncthreads();

        // block max
        float M = wslot[0];
#pragma unroll
        for (int w = 1; w < FPS_NW; ++w) M = fmaxf(M, wslot[w]);

        // index recovery: only threads holding M scan their registers.
        // descending scan keeps the smallest j; cross-thread min via atomicMin
        // -> exact numpy argmax (first occurrence) semantics.
        if (bestv == M) {
            int bj = 0;
#pragma unroll
            for (int i = PAIRS - 1; i >= 0; --i) {
                if (dist2[i].y == M) bj = 2 * i + 1;
                if (dist2[i].x == M) bj = 2 * i;
            }
            atomicMin(&islot[g & 1], (unsigned)(tid + bj * FPS_T));
        }
        __syncthreads();
        far = (int)islot[g & 1];
    }

    // flush centroids to global, coalesced
    float* ctr = out_ctr + (size_t)b * NGRP * 3;
    for (int i = tid; i < NGRP * 3; i += FPS_T) ctr[i] = ctr_lds[i];
}

// --------- kNN keys: exact reference einsum numerics ---------
// xx: separate numpy ufuncs (x**2 then sum) -> sequential rounded ops.
// dot: einsum inner loop FMA-contracted ascending: fma(cz,z, fma(cy,y, rn(cx*x)))
__device__ __forceinline__ unsigned long long knn_key(const float* __restrict__ base,
                                                      int p, float cx, float cy,
                                                      float cz, float cc) {
    float x = base[p * NCH + 0];
    float y = base[p * NCH + 1];
    float z = base[p * NCH + 2];
    float xx = __fadd_rn(__fadd_rn(__fmul_rn(x, x), __fmul_rn(y, y)), __fmul_rn(z, z));
    float dt = fmaf(cz, z, fmaf(cy, y, __fmul_rn(cx, x)));
    float d2 = __fsub_rn(__fadd_rn(cc, xx), __fmul_rn(2.0f, dt));
    unsigned int bits = __float_as_uint(d2);
    unsigned int ord = bits ^ ((unsigned)((int)bits >> 31) | 0x80000000u);
    return ((unsigned long long)ord << 13) | (unsigned)p;
}

// --------- kNN + gather: one wave per (b,g) center ---------
__global__ __launch_bounds__(64) void knn_kernel(const float* __restrict__ pts,
                                                 const float* __restrict__ ctr,
                                                 float* __restrict__ out_nb) {
    const int bg   = blockIdx.x;       // b*NGRP + g
    const int b    = bg >> 9;
    const int lane = threadIdx.x & 63;
    const float* base = pts + (size_t)b * NPTS * NCH;

    const float cx = ctr[bg * 3 + 0];
    const float cy = ctr[bg * 3 + 1];
    const float cz = ctr[bg * 3 + 2];
    const float cc = __fadd_rn(__fadd_rn(__fmul_rn(cx, cx), __fmul_rn(cy, cy)),
                               __fmul_rn(cz, cz));

    // chunk 0 -> bitonic sort 64 keys across the wave (ascending by lane)
    unsigned long long R = knn_key(base, lane, cx, cy, cz, cc);
#pragma unroll
    for (int k = 2; k <= 64; k <<= 1) {
#pragma unroll
        for (int j = k >> 1; j > 0; j >>= 1) {
            unsigned long long o = __shfl_xor(R, j, 64);
            bool takeMin = (((lane & k) == 0) == ((lane & j) == 0));
            unsigned long long mn = (o < R) ? o : R;
            unsigned long long mx = (o < R) ? R : o;
            R = takeMin ? mn : mx;
        }
    }
    unsigned long long R31 = __shfl(R, 31, 64);

    // stream remaining chunks; insert only candidates beating current 32nd
    for (int c = 1; c < NPTS / 64; ++c) {
        unsigned long long key = knn_key(base, c * 64 + lane, cx, cy, cz, cc);
        unsigned long long qual = __ballot(key < R31);
        while (qual) {
            int src = __ffsll(qual) - 1;
            qual &= qual - 1;
            unsigned long long bk = __shfl(key, src, 64);
            int rank = __popcll(__ballot(R < bk));
            unsigned long long Rp = __shfl_up(R, 1, 64);
            R = (lane == rank) ? bk : ((lane > rank) ? Rp : R);
            R31 = __shfl(R, 31, 64);
        }
    }

    // gather: lanes 0..31 hold the sorted top-32 (ascending d2, index tie-break)
    if (lane < KNN) {
        int idx = (int)(R & 8191ULL);
        const float* s = base + (size_t)idx * NCH;
        float* d = out_nb + ((size_t)bg * KNN + lane) * NCH;
        d[0] = s[0] - cx;
        d[1] = s[1] - cy;
        d[2] = s[2] - cz;
        d[3] = s[3];
        d[4] = s[4];
        d[5] = s[5];
    }
}

extern "C" void kernel_launch(void* const* d_in, const int* in_sizes, int n_in,
                              void* d_out, int out_size, void* d_ws, size_t ws_size,
                              hipStream_t stream) {
    const float* pts = (const float*)d_in[0];
    float* out = (float*)d_out;
    float* out_nb  = out;                                    // (8,512,32,6)
    float* out_ctr = out + (size_t)BATCH * NGRP * KNN * NCH; // (8,512,3)

    hipLaunchKernelGGL(fps_kernel, dim3(BATCH), dim3(FPS_T), 0, stream, pts, out_ctr);
    hipLaunchKernelGGL(knn_kernel, dim3(BATCH * NGRP), dim3(64), 0, stream,
                       pts, out_ctr, out_nb);
}

// Round 6
// 513.231 us; speedup vs baseline: 1.4541x; 1.1160x over previous
//
#include <hip/hip_runtime.h>
#include <stdint.h>

#define BATCH 8
#define NPTS 8192
#define NGRP 512
#define KNN 32
#define NCH 6

#define FPS_T 256
#define FPS_PPT (NPTS / FPS_T)   // 32 points per thread
#define PAIRS (FPS_PPT / 2)      // 16 packed pairs
#define FPS_NW (FPS_T / 64)      // 4 waves

#define NBLK 248                 // <= 256 and 1 block/CU (LDS) => all co-resident
#define KNN_WAVES ((NBLK - BATCH) * FPS_NW)   // 960

typedef float f2 __attribute__((ext_vector_type(2)));

// packed f32 ops (VOP3P): 2 points per instruction, IEEE rn per lane —
// bit-identical to scalar __fadd_rn/__fmul_rn. add(x,-c) == sub(x,c) exactly.
__device__ __forceinline__ f2 pk_add(f2 a, f2 b) {
    f2 d;
    asm("v_pk_add_f32 %0, %1, %2" : "=v"(d) : "v"(a), "v"(b));
    return d;
}
__device__ __forceinline__ f2 pk_mul(f2 a, f2 b) {
    f2 d;
    asm("v_pk_mul_f32 %0, %1, %2" : "=v"(d) : "v"(a), "v"(b));
    return d;
}

// 64-bit max butterfly stage via DPP only (no LDS-pipe shuffles).
// Directional reduce: row_shr 1/2/4/8 then row_bcast 15/31 -> lane 63 of the
// wave holds the max. Invalid lanes keep old (= own value) -> max is a no-op.
template <int CTRL>
__device__ __forceinline__ unsigned long long dpp_max64(unsigned long long k) {
    int lo = (int)(unsigned)k;
    int hi = (int)(unsigned)(k >> 32);
    int plo = __builtin_amdgcn_update_dpp(lo, lo, CTRL, 0xF, 0xF, false);
    int phi = __builtin_amdgcn_update_dpp(hi, hi, CTRL, 0xF, 0xF, false);
    unsigned long long o =
        ((unsigned long long)(unsigned)phi << 32) | (unsigned)plo;
    return (o > k) ? o : k;
}

// --------- kNN key: exact reference einsum numerics ---------
// xx: separate numpy ufuncs (x**2 then sum) -> sequential rounded ops.
// dot: einsum inner loop FMA-contracted ascending: fma(cz,z, fma(cy,y, rn(cx*x)))
__device__ __forceinline__ unsigned long long knn_key(const float* __restrict__ base,
                                                      int p, float cx, float cy,
                                                      float cz, float cc) {
    float x = base[p * NCH + 0];
    float y = base[p * NCH + 1];
    float z = base[p * NCH + 2];
    float xx = __fadd_rn(__fadd_rn(__fmul_rn(x, x), __fmul_rn(y, y)), __fmul_rn(z, z));
    float dt = fmaf(cz, z, fmaf(cy, y, __fmul_rn(cx, x)));
    float d2 = __fsub_rn(__fadd_rn(cc, xx), __fmul_rn(2.0f, dt));
    unsigned int bits = __float_as_uint(d2);
    unsigned int ord = bits ^ ((unsigned)((int)bits >> 31) | 0x80000000u);
    return ((unsigned long long)ord << 13) | (unsigned)p;
}

// --------- fused producer-consumer kernel ---------
// blocks [0,8): FPS, one per batch. blocks [8,248): kNN consumer waves that
// spin on faridx[bg] (published at the top of fps iteration g).
__global__ __launch_bounds__(FPS_T) void fused_kernel(const float* __restrict__ pts,
                                                      float* __restrict__ out_ctr,
                                                      float* __restrict__ out_nb,
                                                      unsigned int* __restrict__ faridx,
                                                      int fstride) {
    __shared__ float xs[NPTS], ys[NPTS], zs[NPTS];
    __shared__ float ctr_lds[NGRP * 3];
    __shared__ unsigned long long slots[2][FPS_NW];

    const int tid = threadIdx.x;

    if (blockIdx.x < BATCH) {
        // ================= FPS role =================
        const int b = blockIdx.x;
        const float* base = pts + (size_t)b * NPTS * NCH;

        f2 x2[PAIRS], y2[PAIRS], z2[PAIRS], dist2[PAIRS];
#pragma unroll
        for (int i = 0; i < PAIRS; ++i) {
            int p0 = tid + (2 * i) * FPS_T;
            int p1 = tid + (2 * i + 1) * FPS_T;
            float xa = base[p0 * NCH + 0], ya = base[p0 * NCH + 1], za = base[p0 * NCH + 2];
            float xb = base[p1 * NCH + 0], yb = base[p1 * NCH + 1], zb = base[p1 * NCH + 2];
            x2[i] = (f2){xa, xb};
            y2[i] = (f2){ya, yb};
            z2[i] = (f2){za, zb};
            dist2[i] = (f2){1e10f, 1e10f};
            xs[p0] = xa; ys[p0] = ya; zs[p0] = za;
            xs[p1] = xb; ys[p1] = yb; zs[p1] = zb;
        }
        __syncthreads();

        int far = 0;
        const int wid  = tid >> 6;
        const int lane = tid & 63;

        for (int g = 0; g < NGRP; ++g) {
            // centroid for group g = point `far` (known at top of iter g)
            float cx = xs[far], cy = ys[far], cz = zs[far];
            if (tid == 0) {
                ctr_lds[g * 3 + 0] = cx;
                ctr_lds[g * 3 + 1] = cy;
                ctr_lds[g * 3 + 2] = cz;
                // publish index -> unblocks this center's kNN wave.
                // relaxed is enough: the index alone determines the centroid,
                // and pts is read-only device-wide.
                __hip_atomic_store(&faridx[(b * NGRP + g) * fstride], (unsigned)far,
                                   __ATOMIC_RELAXED, __HIP_MEMORY_SCOPE_AGENT);
            }
            if (g == NGRP - 1) break;   // no further update needed

            f2 ncx = (f2){-cx, -cx};
            f2 ncy = (f2){-cy, -cy};
            f2 ncz = (f2){-cz, -cz};

            // min-dist update + argmax (ascending j, strict > = first index).
            // numpy semantics: (dx^2 + dy^2) + dz^2, each op rn, no FMA.
            float bestv = -1.0f;
            int bestj = 0;
#pragma unroll
            for (int i = 0; i < PAIRS; ++i) {
                f2 dx = pk_add(x2[i], ncx);
                f2 dy = pk_add(y2[i], ncy);
                f2 dz = pk_add(z2[i], ncz);
                f2 sx = pk_mul(dx, dx);
                f2 sy = pk_mul(dy, dy);
                f2 t  = pk_add(sx, sy);
                f2 sz = pk_mul(dz, dz);
                f2 d  = pk_add(t, sz);
                float nd0 = fminf(dist2[i].x, d.x);
                float nd1 = fminf(dist2[i].y, d.y);
                dist2[i].x = nd0;
                dist2[i].y = nd1;
                if (nd0 > bestv) { bestv = nd0; bestj = 2 * i; }
                if (nd1 > bestv) { bestv = nd1; bestj = 2 * i + 1; }
            }
            int bestp = tid + bestj * FPS_T;
            // max-key, min-index tie-break (dist >= 0 -> float bits monotone)
            unsigned long long key =
                ((unsigned long long)__float_as_uint(bestv) << 13) |
                (unsigned)(8191 - bestp);

            // wave max, all-DPP (VALU pipe only): lane 63 gets wave max
            key = dpp_max64<0x111>(key);   // row_shr:1
            key = dpp_max64<0x112>(key);   // row_shr:2
            key = dpp_max64<0x114>(key);   // row_shr:4
            key = dpp_max64<0x118>(key);   // row_shr:8
            key = dpp_max64<0x142>(key);   // row_bcast:15
            key = dpp_max64<0x143>(key);   // row_bcast:31
            if (lane == 63) slots[g & 1][wid] = key;
            __syncthreads();

            unsigned long long best = slots[g & 1][0];
#pragma unroll
            for (int w = 1; w < FPS_NW; ++w) {
                unsigned long long o = slots[g & 1][w];
                best = (o > best) ? o : best;
            }
            far = 8191 - (int)(best & 8191ULL);
        }

        __syncthreads();   // ctr_lds[last] written by tid 0
        // flush centroids to global, coalesced
        float* ctr = out_ctr + (size_t)b * NGRP * 3;
        for (int i = tid; i < NGRP * 3; i += FPS_T) ctr[i] = ctr_lds[i];

    } else {
        // ================= kNN role =================
        const int wid  = tid >> 6;
        const int lane = tid & 63;
        const int W = (blockIdx.x - BATCH) * FPS_NW + wid;   // [0, 960)

        // enumerate centers in ascending-g order (availability order):
        // e = g*8 + b  ->  wave W handles e = W, W+960, ...
        for (int e = W; e < BATCH * NGRP; e += KNN_WAVES) {
            const int g  = e >> 3;
            const int b  = e & 7;
            const int bg = b * NGRP + g;
            const float* base = pts + (size_t)b * NPTS * NCH;

            // spin until fps publishes this center's index
            unsigned fidx;
            if (lane == 0) {
                while ((fidx = __hip_atomic_load(&faridx[bg * fstride],
                                                 __ATOMIC_RELAXED,
                                                 __HIP_MEMORY_SCOPE_AGENT)) == 0xFFFFFFFFu)
                    __builtin_amdgcn_s_sleep(8);
            }
            fidx = (unsigned)__shfl((int)fidx, 0, 64);

            const float cx = base[fidx * NCH + 0];
            const float cy = base[fidx * NCH + 1];
            const float cz = base[fidx * NCH + 2];
            const float cc = __fadd_rn(__fadd_rn(__fmul_rn(cx, cx), __fmul_rn(cy, cy)),
                                       __fmul_rn(cz, cz));

            // chunk 0 -> bitonic sort 64 keys across the wave
            unsigned long long R = knn_key(base, lane, cx, cy, cz, cc);
#pragma unroll
            for (int k = 2; k <= 64; k <<= 1) {
#pragma unroll
                for (int j = k >> 1; j > 0; j >>= 1) {
                    unsigned long long o = __shfl_xor(R, j, 64);
                    bool takeMin = (((lane & k) == 0) == ((lane & j) == 0));
                    unsigned long long mn = (o < R) ? o : R;
                    unsigned long long mx = (o < R) ? R : o;
                    R = takeMin ? mn : mx;
                }
            }
            unsigned long long R31 = __shfl(R, 31, 64);

            // stream remaining chunks; insert candidates beating current 32nd
            for (int c = 1; c < NPTS / 64; ++c) {
                unsigned long long key = knn_key(base, c * 64 + lane, cx, cy, cz, cc);
                unsigned long long qual = __ballot(key < R31);
                while (qual) {
                    int src = __ffsll(qual) - 1;
                    qual &= qual - 1;
                    unsigned long long bk = __shfl(key, src, 64);
                    int rank = __popcll(__ballot(R < bk));
                    unsigned long long Rp = __shfl_up(R, 1, 64);
                    R = (lane == rank) ? bk : ((lane > rank) ? Rp : R);
                    R31 = __shfl(R, 31, 64);
                }
            }

            // gather: lanes 0..31 hold the sorted top-32
            if (lane < KNN) {
                int idx = (int)(R & 8191ULL);
                const float* s = base + (size_t)idx * NCH;
                float* d = out_nb + ((size_t)bg * KNN + lane) * NCH;
                d[0] = s[0] - cx;
                d[1] = s[1] - cy;
                d[2] = s[2] - cz;
                d[3] = s[3];
                d[4] = s[4];
                d[5] = s[5];
            }
        }
    }
}

extern "C" void kernel_launch(void* const* d_in, const int* in_sizes, int n_in,
                              void* d_out, int out_size, void* d_ws, size_t ws_size,
                              hipStream_t stream) {
    const float* pts = (const float*)d_in[0];
    float* out = (float*)d_out;
    float* out_nb  = out;                                    // (8,512,32,6)
    float* out_ctr = out + (size_t)BATCH * NGRP * KNN * NCH; // (8,512,3)

    // per-center published index; 64B stride => 1 writer + 1 reader per line
    const size_t nctr = (size_t)BATCH * NGRP;
    int fstride = (ws_size >= nctr * 16 * sizeof(unsigned)) ? 16 : 1;
    unsigned int* faridx = (unsigned int*)d_ws;

    hipMemsetAsync(d_ws, 0xFF, nctr * (size_t)fstride * sizeof(unsigned), stream);
    hipLaunchKernelGGL(fused_kernel, dim3(NBLK), dim3(FPS_T), 0, stream,
                       pts, out_ctr, out_nb, faridx, fstride);
}

// Round 7
// 502.716 us; speedup vs baseline: 1.4845x; 1.0209x over previous
//
#include <hip/hip_runtime.h>
#include <stdint.h>

#define BATCH 8
#define NPTS 8192
#define NGRP 512
#define KNN 32
#define NCH 6

#define FPS_T 256
#define FPS_PPT (NPTS / FPS_T)   // 32 points per thread
#define PAIRS (FPS_PPT / 2)      // 16 packed pairs
#define FPS_NW (FPS_T / 64)      // 4 waves

#define NBLK 248                 // <= 256 and 1 block/CU (LDS) => all co-resident
#define KNN_WAVES ((NBLK - BATCH) * FPS_NW)   // 960

typedef float f2 __attribute__((ext_vector_type(2)));

// packed f32 ops (VOP3P): 2 points per instruction, IEEE rn per lane —
// bit-identical to scalar __fadd_rn/__fmul_rn. add(x,-c) == sub(x,c) exactly.
__device__ __forceinline__ f2 pk_add(f2 a, f2 b) {
    f2 d;
    asm("v_pk_add_f32 %0, %1, %2" : "=v"(d) : "v"(a), "v"(b));
    return d;
}
__device__ __forceinline__ f2 pk_mul(f2 a, f2 b) {
    f2 d;
    asm("v_pk_mul_f32 %0, %1, %2" : "=v"(d) : "v"(a), "v"(b));
    return d;
}

// 64-bit max butterfly stage via DPP only (no LDS-pipe shuffles).
// Directional reduce: row_shr 1/2/4/8 then row_bcast 15/31 -> lane 63 of the
// wave holds the max. Invalid lanes keep old (= own value) -> max is a no-op.
template <int CTRL>
__device__ __forceinline__ unsigned long long dpp_max64(unsigned long long k) {
    int lo = (int)(unsigned)k;
    int hi = (int)(unsigned)(k >> 32);
    int plo = __builtin_amdgcn_update_dpp(lo, lo, CTRL, 0xF, 0xF, false);
    int phi = __builtin_amdgcn_update_dpp(hi, hi, CTRL, 0xF, 0xF, false);
    unsigned long long o =
        ((unsigned long long)(unsigned)phi << 32) | (unsigned)plo;
    return (o > k) ? o : k;
}

// --------- kNN key: exact reference einsum numerics ---------
// xx: separate numpy ufuncs (x**2 then sum) -> sequential rounded ops.
// dot: einsum inner loop FMA-contracted ascending: fma(cz,z, fma(cy,y, rn(cx*x)))
__device__ __forceinline__ unsigned long long knn_key(const float* __restrict__ base,
                                                      int p, float cx, float cy,
                                                      float cz, float cc) {
    float x = base[p * NCH + 0];
    float y = base[p * NCH + 1];
    float z = base[p * NCH + 2];
    float xx = __fadd_rn(__fadd_rn(__fmul_rn(x, x), __fmul_rn(y, y)), __fmul_rn(z, z));
    float dt = fmaf(cz, z, fmaf(cy, y, __fmul_rn(cx, x)));
    float d2 = __fsub_rn(__fadd_rn(cc, xx), __fmul_rn(2.0f, dt));
    unsigned int bits = __float_as_uint(d2);
    unsigned int ord = bits ^ ((unsigned)((int)bits >> 31) | 0x80000000u);
    return ((unsigned long long)ord << 13) | (unsigned)p;
}

// --------- fused producer-consumer kernel ---------
// blocks [0,8): FPS, one per batch. blocks [8,248): kNN consumer waves that
// HOT-spin (packed-FMA burn between polls -> keeps CUs busy so the DVFS
// governor holds high clock; s_sleep spinning left the chip at ~2% util and
// the serial FPS chain ran at an apparently-reduced clock).
__global__ __launch_bounds__(FPS_T) void fused_kernel(const float* __restrict__ pts,
                                                      float* __restrict__ out_ctr,
                                                      float* __restrict__ out_nb,
                                                      unsigned int* __restrict__ faridx,
                                                      int fstride) {
    __shared__ float xs[NPTS], ys[NPTS], zs[NPTS];
    __shared__ float ctr_lds[NGRP * 3];
    __shared__ unsigned long long slots[2][FPS_NW];

    const int tid = threadIdx.x;

    if (blockIdx.x < BATCH) {
        // ================= FPS role =================
        const int b = blockIdx.x;
        const float* base = pts + (size_t)b * NPTS * NCH;

        f2 x2[PAIRS], y2[PAIRS], z2[PAIRS], dist2[PAIRS];
#pragma unroll
        for (int i = 0; i < PAIRS; ++i) {
            int p0 = tid + (2 * i) * FPS_T;
            int p1 = tid + (2 * i + 1) * FPS_T;
            float xa = base[p0 * NCH + 0], ya = base[p0 * NCH + 1], za = base[p0 * NCH + 2];
            float xb = base[p1 * NCH + 0], yb = base[p1 * NCH + 1], zb = base[p1 * NCH + 2];
            x2[i] = (f2){xa, xb};
            y2[i] = (f2){ya, yb};
            z2[i] = (f2){za, zb};
            dist2[i] = (f2){1e10f, 1e10f};
            xs[p0] = xa; ys[p0] = ya; zs[p0] = za;
            xs[p1] = xb; ys[p1] = yb; zs[p1] = zb;
        }
        __syncthreads();

        int far = 0;
        const int wid  = tid >> 6;
        const int lane = tid & 63;

        for (int g = 0; g < NGRP; ++g) {
            // centroid for group g = point `far` (known at top of iter g)
            float cx = xs[far], cy = ys[far], cz = zs[far];
            if (tid == 0) {
                ctr_lds[g * 3 + 0] = cx;
                ctr_lds[g * 3 + 1] = cy;
                ctr_lds[g * 3 + 2] = cz;
                // publish index -> unblocks this center's kNN wave.
                // relaxed is enough: the index alone determines the centroid,
                // and pts is read-only device-wide.
                __hip_atomic_store(&faridx[(b * NGRP + g) * fstride], (unsigned)far,
                                   __ATOMIC_RELAXED, __HIP_MEMORY_SCOPE_AGENT);
            }
            if (g == NGRP - 1) break;   // no further update needed

            f2 ncx = (f2){-cx, -cx};
            f2 ncy = (f2){-cy, -cy};
            f2 ncz = (f2){-cz, -cz};

            // min-dist update + argmax (ascending j, strict > = first index).
            // numpy semantics: (dx^2 + dy^2) + dz^2, each op rn, no FMA.
            float bestv = -1.0f;
            int bestj = 0;
#pragma unroll
            for (int i = 0; i < PAIRS; ++i) {
                f2 dx = pk_add(x2[i], ncx);
                f2 dy = pk_add(y2[i], ncy);
                f2 dz = pk_add(z2[i], ncz);
                f2 sx = pk_mul(dx, dx);
                f2 sy = pk_mul(dy, dy);
                f2 t  = pk_add(sx, sy);
                f2 sz = pk_mul(dz, dz);
                f2 d  = pk_add(t, sz);
                float nd0 = fminf(dist2[i].x, d.x);
                float nd1 = fminf(dist2[i].y, d.y);
                dist2[i].x = nd0;
                dist2[i].y = nd1;
                if (nd0 > bestv) { bestv = nd0; bestj = 2 * i; }
                if (nd1 > bestv) { bestv = nd1; bestj = 2 * i + 1; }
            }
            int bestp = tid + bestj * FPS_T;
            // max-key, min-index tie-break (dist >= 0 -> float bits monotone)
            unsigned long long key =
                ((unsigned long long)__float_as_uint(bestv) << 13) |
                (unsigned)(8191 - bestp);

            // wave max, all-DPP (VALU pipe only): lane 63 gets wave max
            key = dpp_max64<0x111>(key);   // row_shr:1
            key = dpp_max64<0x112>(key);   // row_shr:2
            key = dpp_max64<0x114>(key);   // row_shr:4
            key = dpp_max64<0x118>(key);   // row_shr:8
            key = dpp_max64<0x142>(key);   // row_bcast:15
            key = dpp_max64<0x143>(key);   // row_bcast:31
            if (lane == 63) slots[g & 1][wid] = key;
            __syncthreads();

            unsigned long long best = slots[g & 1][0];
#pragma unroll
            for (int w = 1; w < FPS_NW; ++w) {
                unsigned long long o = slots[g & 1][w];
                best = (o > best) ? o : best;
            }
            far = 8191 - (int)(best & 8191ULL);
        }

        __syncthreads();   // ctr_lds[last] written by tid 0
        // flush centroids to global, coalesced
        float* ctr = out_ctr + (size_t)b * NGRP * 3;
        for (int i = tid; i < NGRP * 3; i += FPS_T) ctr[i] = ctr_lds[i];

    } else {
        // ================= kNN role =================
        const int wid  = tid >> 6;
        const int lane = tid & 63;
        const int W = (blockIdx.x - BATCH) * FPS_NW + wid;   // [0, 960)

        // enumerate centers in ascending-g order (availability order):
        // e = g*8 + b  ->  wave W handles e = W, W+960, ...
        for (int e = W; e < BATCH * NGRP; e += KNN_WAVES) {
            const int g  = e >> 3;
            const int b  = e & 7;
            const int bg = b * NGRP + g;
            const float* base = pts + (size_t)b * NPTS * NCH;

            // HOT spin until fps publishes this center's index. All lanes load
            // the same address (one request); between polls burn packed FMAs
            // to keep the CU (and the chip's DVFS governor) fully active.
            unsigned fidx;
            {
                f2 burn = (f2){(float)lane, (float)wid};
                const f2 k1 = (f2){1.0000001f, 0.9999999f};
                const f2 k2 = (f2){0.0625f, 0.03125f};
                while (true) {
                    fidx = __hip_atomic_load(&faridx[bg * fstride],
                                             __ATOMIC_RELAXED,
                                             __HIP_MEMORY_SCOPE_AGENT);
                    if (fidx != 0xFFFFFFFFu) break;
#pragma unroll
                    for (int r = 0; r < 32; ++r) {
                        burn = pk_add(pk_mul(burn, k1), k2);
                    }
                    asm volatile("" : "+v"(burn));   // keep live, no DCE
                }
            }

            const float cx = base[fidx * NCH + 0];
            const float cy = base[fidx * NCH + 1];
            const float cz = base[fidx * NCH + 2];
            const float cc = __fadd_rn(__fadd_rn(__fmul_rn(cx, cx), __fmul_rn(cy, cy)),
                                       __fmul_rn(cz, cz));

            // chunk 0 -> bitonic sort 64 keys across the wave
            unsigned long long R = knn_key(base, lane, cx, cy, cz, cc);
#pragma unroll
            for (int k = 2; k <= 64; k <<= 1) {
#pragma unroll
                for (int j = k >> 1; j > 0; j >>= 1) {
                    unsigned long long o = __shfl_xor(R, j, 64);
                    bool takeMin = (((lane & k) == 0) == ((lane & j) == 0));
                    unsigned long long mn = (o < R) ? o : R;
                    unsigned long long mx = (o < R) ? R : o;
                    R = takeMin ? mn : mx;
                }
            }
            unsigned long long R31 = __shfl(R, 31, 64);

            // stream remaining chunks; insert candidates beating current 32nd
            for (int c = 1; c < NPTS / 64; ++c) {
                unsigned long long key = knn_key(base, c * 64 + lane, cx, cy, cz, cc);
                unsigned long long qual = __ballot(key < R31);
                while (qual) {
                    int src = __ffsll(qual) - 1;
                    qual &= qual - 1;
                    unsigned long long bk = __shfl(key, src, 64);
                    int rank = __popcll(__ballot(R < bk));
                    unsigned long long Rp = __shfl_up(R, 1, 64);
                    R = (lane == rank) ? bk : ((lane > rank) ? Rp : R);
                    R31 = __shfl(R, 31, 64);
                }
            }

            // gather: lanes 0..31 hold the sorted top-32
            if (lane < KNN) {
                int idx = (int)(R & 8191ULL);
                const float* s = base + (size_t)idx * NCH;
                float* d = out_nb + ((size_t)bg * KNN + lane) * NCH;
                d[0] = s[0] - cx;
                d[1] = s[1] - cy;
                d[2] = s[2] - cz;
                d[3] = s[3];
                d[4] = s[4];
                d[5] = s[5];
            }
        }
    }
}

extern "C" void kernel_launch(void* const* d_in, const int* in_sizes, int n_in,
                              void* d_out, int out_size, void* d_ws, size_t ws_size,
                              hipStream_t stream) {
    const float* pts = (const float*)d_in[0];
    float* out = (float*)d_out;
    float* out_nb  = out;                                    // (8,512,32,6)
    float* out_ctr = out + (size_t)BATCH * NGRP * KNN * NCH; // (8,512,3)

    // per-center published index; 64B stride => 1 writer + 1 reader per line
    const size_t nctr = (size_t)BATCH * NGRP;
    int fstride = (ws_size >= nctr * 16 * sizeof(unsigned)) ? 16 : 1;
    unsigned int* faridx = (unsigned int*)d_ws;

    hipMemsetAsync(d_ws, 0xFF, nctr * (size_t)fstride * sizeof(unsigned), stream);
    hipLaunchKernelGGL(fused_kernel, dim3(NBLK), dim3(FPS_T), 0, stream,
                       pts, out_ctr, out_nb, faridx, fstride);
}